// Round 8
// baseline (214.250 us; speedup 1.0000x reference)
//
#include <hip/hip_runtime.h>

#define LDIM 4096
#define DDIM 64
#define KCODES 1024
#define BDIM 16
#define NROWS 65536   // BDIM * LDIM
#define NSLICE 8
#define SLICE_ROWS (NROWS / NSLICE)   // 8192
#define CHUNK_SHORTS 16384            // 32 KB = 4 tiles of 32 codes

typedef __attribute__((ext_vector_type(8))) short short8;
typedef __attribute__((ext_vector_type(16))) float float16v;

__device__ __forceinline__ unsigned int orderf(float f) {
  unsigned int u = __float_as_uint(f);
  return (u & 0x80000000u) ? ~u : (u | 0x80000000u);
}

__device__ __forceinline__ unsigned long long shfl_xor_u64(unsigned long long v, int m) {
  int lo = __shfl_xor((int)(unsigned int)(v & 0xffffffffull), m, 64);
  int hi = __shfl_xor((int)(unsigned int)(v >> 32), m, 64);
  return ((unsigned long long)(unsigned int)hi << 32) | (unsigned int)lo;
}

// bf16 RNE high part (as ushort bits)
__device__ __forceinline__ unsigned int bf16_rne(float x) {
  unsigned int u = __float_as_uint(x);
  return (u + 0x7FFFu + ((u >> 16) & 1u)) >> 16;
}

// async global->LDS, 16B per lane; lds dst is wave-uniform base (HW adds lane*16)
__device__ __forceinline__ void gload_lds16(const unsigned short* g, unsigned short* l) {
  __builtin_amdgcn_global_load_lds(
      (const __attribute__((address_space(1))) unsigned int*)g,
      (__attribute__((address_space(3))) unsigned int*)l, 16, 0, 0);
}

// ---------------------------------------------------------------------------
// prep: per-code norm + softmax table + FRAGMENT-LOAD-ORDER bf16 codebook.
// Also zeroes klacc (replaces the hipMemsetAsync dispatch).
// ---------------------------------------------------------------------------
__global__ void prep_kernel(const float* __restrict__ Ew,
                            float* __restrict__ enorm,
                            float* __restrict__ SE,
                            unsigned short* __restrict__ Epk2,
                            float* __restrict__ klacc) {
  int k = blockIdx.x;
  int d = threadIdx.x;
  if (k == 0 && d == 0) *klacc = 0.f;
  float v = Ew[k * DDIM + d];
  float n2 = v * v;
  #pragma unroll
  for (int o = 32; o > 0; o >>= 1) n2 += __shfl_xor(n2, o, 64);
  float m = v;
  #pragma unroll
  for (int o = 32; o > 0; o >>= 1) m = fmaxf(m, __shfl_xor(m, o, 64));
  float e = __expf(v - m);
  float Z = e;
  #pragma unroll
  for (int o = 32; o > 0; o >>= 1) Z += __shfl_xor(Z, o, 64);
  SE[k * DDIM + d] = e / Z;
  if (d == 0) enorm[k] = n2;

  unsigned int rh = bf16_rne(v);
  float hif = __uint_as_float(rh << 16);
  unsigned int rl = bf16_rne(v - hif);
  int tile = k >> 5, mm = k & 31;
  int s = d >> 4, h = (d >> 3) & 1, j = d & 7;
  int base = tile * 4096 + (h * 32 + mm) * 8 + j;
  Epk2[base + s * 512]        = (unsigned short)rh;
  Epk2[base + (4 + s) * 512]  = (unsigned short)rl;
}

// ---------------------------------------------------------------------------
// argmin FUSED (R8): double-buffered async LDS staging of the codebook.
// 512 blocks x 4 waves x 32 rows (R3 shape). Codebook scanned as 8 chunks of
// 32 KB (4 tiles each), staged via global_load_lds into cb0/cb1 ping-pong:
// chunk c+1's loads are ISSUED before computing chunk c's tiles, so the
// ~L2/HBM latency hides under 4 tiles of MFMA+VALU. __syncthreads() at the
// iteration end drains vmcnt (compiler emits the waitcnt) and flips buffers.
// 3 independent 4-deep MFMA chains (a0/a1/a2). Fused epilogue = R3-verified.
// ---------------------------------------------------------------------------
__launch_bounds__(256, 2)
__global__ void argmin_fused_kernel(const float* __restrict__ inp,
                                    const unsigned short* __restrict__ Epk2,
                                    const float* __restrict__ enorm,
                                    const float* __restrict__ SE,
                                    const float* __restrict__ Ew,
                                    int* __restrict__ idx_ws,
                                    float* __restrict__ outidx,
                                    float* __restrict__ out,
                                    float* __restrict__ klacc) {
  __shared__ unsigned short cb0[CHUNK_SHORTS];   // 32 KB
  __shared__ unsigned short cb1[CHUNK_SHORTS];   // 32 KB

  const int tid = threadIdx.x;
  const int lane = tid & 63;
  const int w = tid >> 6;
  const int half = lane >> 5;
  const int m = lane & 31;
  const int row_base = blockIdx.x * 128 + w * 32;
  const int b = row_base >> 12;
  const int l0 = row_base & 4095;
  const float* xp = inp + (size_t)b * DDIM * LDIM + l0 + m;

  // ---- issue chunk 0 staging first (latency overlaps the x-prologue) ----
  {
    const unsigned short* src = Epk2 + w * 4096;
    unsigned short* dst0 = cb0 + w * 4096;
    #pragma unroll
    for (int it = 0; it < 8; ++it)
      gload_lds16(src + it * 512 + lane * 8, dst0 + it * 512);
  }

  short8 afr[8];
  float ex[4][8];          // e^x, statically indexed only (rule #20)
  float Zp = 0.f, S1p = 0.f;
  #pragma unroll
  for (int s = 0; s < 4; s++) {
    #pragma unroll
    for (int j = 0; j < 8; j++) {
      int d = 16 * s + 8 * half + j;
      float x = xp[(size_t)d * LDIM];
      float e = __expf(x);
      ex[s][j] = e;
      Zp += e;
      S1p = fmaf(e, x, S1p);
      unsigned int rh = bf16_rne(x);
      float hif = __uint_as_float(rh << 16);
      unsigned int rl = bf16_rne(x - hif);
      afr[s][j] = (short)(unsigned short)rh;
      afr[4 + s][j] = (short)(unsigned short)rl;
    }
  }

  float bsc[16];
  int bix[16];
  #pragma unroll
  for (int j = 0; j < 16; j++) { bsc[j] = 1e30f; bix[j] = 0; }

  float16v zacc = {};   // persistent zero C-in for first MFMA of each chain

  __syncthreads();      // chunk 0 resident (syncthreads drains vmcnt)

  #pragma unroll 2
  for (int c = 0; c < 8; ++c) {
    unsigned short* cur = (c & 1) ? cb1 : cb0;
    if (c < 7) {
      // async-issue next chunk into the other buffer; completes under compute
      const unsigned short* src = Epk2 + (size_t)(c + 1) * CHUNK_SHORTS + w * 4096;
      unsigned short* nxt = ((c & 1) ? cb0 : cb1) + w * 4096;
      #pragma unroll
      for (int it = 0; it < 8; ++it)
        gload_lds16(src + it * 512 + lane * 8, nxt + it * 512);
    }

    #pragma unroll
    for (int tt = 0; tt < 4; ++tt) {
      const int t = c * 4 + tt;
      const unsigned short* cbp = cur + tt * 4096 + lane * 8;
      short8 bA[8];
      #pragma unroll
      for (int s = 0; s < 4; s++) {
        bA[s]     = *(const short8*)(cbp + s * 512);
        bA[4 + s] = *(const short8*)(cbp + 2048 + s * 512);
      }
      float en = enorm[t * 32 + m];

      float16v a0 = __builtin_amdgcn_mfma_f32_32x32x16_bf16(afr[0], bA[0], zacc, 0, 0, 0);
      float16v a1 = __builtin_amdgcn_mfma_f32_32x32x16_bf16(afr[0], bA[4], zacc, 0, 0, 0);
      float16v a2 = __builtin_amdgcn_mfma_f32_32x32x16_bf16(afr[4], bA[0], zacc, 0, 0, 0);
      #pragma unroll
      for (int s = 1; s < 4; s++) {
        a0 = __builtin_amdgcn_mfma_f32_32x32x16_bf16(afr[s], bA[s], a0, 0, 0, 0);
        a1 = __builtin_amdgcn_mfma_f32_32x32x16_bf16(afr[s], bA[4 + s], a1, 0, 0, 0);
        a2 = __builtin_amdgcn_mfma_f32_32x32x16_bf16(afr[4 + s], bA[s], a2, 0, 0, 0);
      }
      const int ci = t * 32 + m;
      #pragma unroll
      for (int j = 0; j < 16; j++) {
        float sc = fmaf(-2.f, a0[j] + a1[j] + a2[j], en);
        if (sc < bsc[j]) { bsc[j] = sc; bix[j] = ci; }  // ascending ci: ties -> smaller
      }
    }
    __syncthreads();   // drains staging vmcnt; safe to overwrite cur next iter
  }

  // -------- per-row winner keys + fused epilogue (R3-verified) --------
  // Row m is held in key slot j_r of half h_r:
  const int jr = (m & 3) | ((m >> 3) << 2);
  const int hr = (m >> 2) & 1;
  unsigned long long mykey = 0ull;

  #pragma unroll
  for (int j = 0; j < 16; j++) {
    unsigned long long key =
        ((unsigned long long)orderf(bsc[j]) << 32) | (unsigned int)bix[j];
    #pragma unroll
    for (int mm = 1; mm < 32; mm <<= 1) {
      unsigned long long o = shfl_xor_u64(key, mm);
      if (o < key) key = o;
    }
    if (j == jr) mykey = key;   // static unroll: cndmask, no scratch
  }
  unsigned long long partner = shfl_xor_u64(mykey, 32);
  unsigned long long keyrow = (hr == half) ? mykey : partner;
  const int kr = (int)(keyrow & 0xffffffffull);

  if (half == 0) {
    idx_ws[row_base + m] = kr;
    outidx[row_base + m] = (float)kr;
  }

  // U = sum_d e^{x_d} * SE[kr][d]  (this thread's 32 d's), and out stores
  float Up = 0.f;
  const float* sebase = SE + kr * DDIM + 8 * half;
  const float* ewbase = Ew + kr * DDIM + 8 * half;
  float* obase = out + (size_t)b * DDIM * LDIM + l0 + m;
  #pragma unroll
  for (int s = 0; s < 4; s++) {
    float4 q0 = *(const float4*)(sebase + 16 * s);
    float4 q1 = *(const float4*)(sebase + 16 * s + 4);
    Up = fmaf(ex[s][0], q0.x, Up); Up = fmaf(ex[s][1], q0.y, Up);
    Up = fmaf(ex[s][2], q0.z, Up); Up = fmaf(ex[s][3], q0.w, Up);
    Up = fmaf(ex[s][4], q1.x, Up); Up = fmaf(ex[s][5], q1.y, Up);
    Up = fmaf(ex[s][6], q1.z, Up); Up = fmaf(ex[s][7], q1.w, Up);
    float4 e0 = *(const float4*)(ewbase + 16 * s);
    float4 e1 = *(const float4*)(ewbase + 16 * s + 4);
    const int d0 = 16 * s + 8 * half;
    obase[(size_t)(d0 + 0) * LDIM] = e0.x;
    obase[(size_t)(d0 + 1) * LDIM] = e0.y;
    obase[(size_t)(d0 + 2) * LDIM] = e0.z;
    obase[(size_t)(d0 + 3) * LDIM] = e0.w;
    obase[(size_t)(d0 + 4) * LDIM] = e1.x;
    obase[(size_t)(d0 + 5) * LDIM] = e1.y;
    obase[(size_t)(d0 + 6) * LDIM] = e1.z;
    obase[(size_t)(d0 + 7) * LDIM] = e1.w;
  }

  // combine half-pair (disjoint d-subsets), then per-wave KL sum
  float Z = Zp + __shfl_xor(Zp, 32, 64);
  float S1 = S1p + __shfl_xor(S1p, 32, 64);
  float U = Up + __shfl_xor(Up, 32, 64);
  float kl = (S1 - U) / Z - __logf(Z);
  kl = (half == 0) ? kl : 0.f;
  #pragma unroll
  for (int o = 1; o < 64; o <<= 1) kl += __shfl_xor(kl, o, 64);
  if (lane == 0) atomicAdd(klacc, kl);   // non-returning: no wave stall
}

// ---------------------------------------------------------------------------
// dw: dimension-sliced LDS histogram. 512 threads/block, fully-unrolled
// float4/int4 loads. (Unchanged from R7-verified.)
// ---------------------------------------------------------------------------
__launch_bounds__(512)
__global__ void dw_kernel(const float* __restrict__ inp,
                          const int* __restrict__ idx_ws,
                          float* __restrict__ partial,
                          float* __restrict__ pcounts) {
  __shared__ float dwp[KCODES];
  __shared__ float cnt[KCODES];
  const int tid = threadIdx.x;
  const int d = blockIdx.x & 63;
  const int slice = blockIdx.x >> 6;
  const bool do_cnt = (d == 0);

  #pragma unroll
  for (int i = 0; i < KCODES / 512; i++) {
    dwp[tid + i * 512] = 0.f;
    cnt[tid + i * 512] = 0.f;
  }
  __syncthreads();

  const int r0 = slice * SLICE_ROWS;
  #pragma unroll
  for (int j = 0; j < 4; j++) {
    const int rbase = r0 + j * 2048 + tid * 4;
    const int bb = rbase >> 12;
    const int ll = rbase & 4095;
    const float4 xv = *(const float4*)(inp + (size_t)bb * DDIM * LDIM +
                                       (size_t)d * LDIM + ll);
    const int4 kv = *(const int4*)(idx_ws + rbase);
    atomicAdd(&dwp[kv.x], xv.x);
    atomicAdd(&dwp[kv.y], xv.y);
    atomicAdd(&dwp[kv.z], xv.z);
    atomicAdd(&dwp[kv.w], xv.w);
    if (do_cnt) {
      atomicAdd(&cnt[kv.x], 1.0f);
      atomicAdd(&cnt[kv.y], 1.0f);
      atomicAdd(&cnt[kv.z], 1.0f);
      atomicAdd(&cnt[kv.w], 1.0f);
    }
  }
  __syncthreads();

  float* dst = partial + ((size_t)slice * 64 + d) * KCODES;
  #pragma unroll
  for (int i = 0; i < KCODES / 512; i++) dst[tid + i * 512] = dwp[tid + i * 512];
  if (do_cnt) {
    float* cd = pcounts + (size_t)slice * KCODES;
    #pragma unroll
    for (int i = 0; i < KCODES / 512; i++) cd[tid + i * 512] = cnt[tid + i * 512];
  }
}

// ---------------------------------------------------------------------------
// finalize: COALESCED mapping (R7-verified). Block b -> d = b>>2,
// k = (b&3)*256+tid; partial/pcounts/emacs reads contiguous along k.
// ---------------------------------------------------------------------------
__launch_bounds__(256)
__global__ void finalize_kernel(const float* __restrict__ partial,
                                const float* __restrict__ pcounts,
                                const float* __restrict__ emaw,
                                const float* __restrict__ emacs,
                                const float* __restrict__ klacc,
                                float* __restrict__ emb_out,
                                float* __restrict__ loss_out,
                                float* __restrict__ perp_out) {
  __shared__ float red[4], red2[4];
  const int tid = threadIdx.x;
  const int d = blockIdx.x >> 2;
  const int k = ((blockIdx.x & 3) << 8) + tid;

  float se = 0.f;
  #pragma unroll
  for (int t = 0; t < 4; t++) se += emacs[tid * 4 + t];
  #pragma unroll
  for (int o = 32; o > 0; o >>= 1) se += __shfl_xor(se, o, 64);
  if ((tid & 63) == 0) red[tid >> 6] = se;
  __syncthreads();
  const float S = red[0] + red[1] + red[2] + red[3];
  const float N = 0.9f * S + 0.1f * (float)NROWS;

  float c = 0.f;
  #pragma unroll
  for (int sl = 0; sl < NSLICE; sl++) c += pcounts[sl * KCODES + k];
  float cs = fmaf(0.1f, c, emacs[k] * 0.9f);
  float csp = (cs + 1e-5f) / (N + (float)KCODES * 1e-5f) * N;

  float s = 0.f;
  #pragma unroll
  for (int sl = 0; sl < NSLICE; sl++)
    s += partial[((size_t)sl * 64 + d) * KCODES + k];
  emb_out[k * DDIM + d] = fmaf(0.1f, s, emaw[k * DDIM + d] * 0.9f) / csp;

  if (blockIdx.x == 0) {
    float es = 0.f;
    #pragma unroll
    for (int t = 0; t < 4; t++) {
      int kk = tid * 4 + t;
      float cc = 0.f;
      #pragma unroll
      for (int sl = 0; sl < NSLICE; sl++) cc += pcounts[sl * KCODES + kk];
      float a = cc * (1.0f / (float)NROWS);
      es += a * logf(a + 1e-10f);
    }
    #pragma unroll
    for (int o = 32; o > 0; o >>= 1) es += __shfl_xor(es, o, 64);
    if ((tid & 63) == 0) red2[tid >> 6] = es;
    __syncthreads();
    if (tid == 0) {
      *perp_out = expf(-(red2[0] + red2[1] + red2[2] + red2[3]));
      *loss_out = 0.1f * (*klacc) * (1.0f / 16.0f);
    }
  }
}

extern "C" void kernel_launch(void* const* d_in, const int* in_sizes, int n_in,
                              void* d_out, int out_size, void* d_ws, size_t ws_size,
                              hipStream_t stream) {
  const float* inp   = (const float*)d_in[0];   // (16,64,4096)
  const float* Ew    = (const float*)d_in[1];   // (1024,64)
  const float* emacs = (const float*)d_in[2];   // (1024,)
  const float* emaw  = (const float*)d_in[3];   // (1024,64)

  float* out      = (float*)d_out;              // (16,64,4096) = 4194304
  float* loss_out = out + 4194304;
  float* perp_out = out + 4194305;
  float* emb_out  = out + 4194306;              // 65536
  float* idxf_out = out + 4194306 + 65536;      // 65536 (indices as float)

  char* ws = (char*)d_ws;
  int*   idx_ws  = (int*)(ws);                  // 262144 B
  float* klacc   = (float*)(ws + 262144);       // 256 B (zeroed by prep)
  float* enorm   = (float*)(ws + 266496);       // 4096 B
  float* SE      = (float*)(ws + 274688);       // 262144 B -> ends 536832
  unsigned short* Epk2 = (unsigned short*)(ws + 536832);  // 262144 B
  // dw partials alias Epk2 (dead after argmin)
  float* partial = (float*)(ws + 536832);       // 2097152 B -> ends 2633984
  float* pcounts = (float*)(ws + 2633984);      // 32768 B  -> ends 2666752

  prep_kernel<<<KCODES, 64, 0, stream>>>(Ew, enorm, SE, Epk2, klacc);
  argmin_fused_kernel<<<512, 256, 0, stream>>>(inp, Epk2, enorm, SE, Ew,
                                               idx_ws, idxf_out, out, klacc);
  dw_kernel<<<512, 512, 0, stream>>>(inp, idx_ws, partial, pcounts);
  finalize_kernel<<<NROWS / 256, 256, 0, stream>>>(partial, pcounts, emaw, emacs,
                                                   klacc, emb_out, loss_out,
                                                   perp_out);
}

// Round 9
// 172.365 us; speedup vs baseline: 1.2430x; 1.2430x over previous
//
#include <hip/hip_runtime.h>

#define LDIM 4096
#define DDIM 64
#define KCODES 1024
#define BDIM 16
#define NROWS 65536   // BDIM * LDIM
#define NSLICE 8
#define SLICE_ROWS (NROWS / NSLICE)   // 8192
#define CHUNK_SHORTS 8192             // 16 KB = 2 tiles of 32 codes

typedef __attribute__((ext_vector_type(8))) short short8;
typedef __attribute__((ext_vector_type(16))) float float16v;

__device__ __forceinline__ unsigned int orderf(float f) {
  unsigned int u = __float_as_uint(f);
  return (u & 0x80000000u) ? ~u : (u | 0x80000000u);
}

__device__ __forceinline__ unsigned long long shfl_xor_u64(unsigned long long v, int m) {
  int lo = __shfl_xor((int)(unsigned int)(v & 0xffffffffull), m, 64);
  int hi = __shfl_xor((int)(unsigned int)(v >> 32), m, 64);
  return ((unsigned long long)(unsigned int)hi << 32) | (unsigned int)lo;
}

// bf16 RNE high part (as ushort bits)
__device__ __forceinline__ unsigned int bf16_rne(float x) {
  unsigned int u = __float_as_uint(x);
  return (u + 0x7FFFu + ((u >> 16) & 1u)) >> 16;
}

// async global->LDS, 16B per lane; lds dst is wave-uniform base (HW adds lane*16)
__device__ __forceinline__ void gload_lds16(const unsigned short* g, unsigned short* l) {
  __builtin_amdgcn_global_load_lds(
      (const __attribute__((address_space(1))) unsigned int*)g,
      (__attribute__((address_space(3))) unsigned int*)l, 16, 0, 0);
}

// ---------------------------------------------------------------------------
// prep: per-code norm + softmax table + FRAGMENT-LOAD-ORDER bf16 codebook.
// Also zeroes klacc.
// ---------------------------------------------------------------------------
__global__ void prep_kernel(const float* __restrict__ Ew,
                            float* __restrict__ enorm,
                            float* __restrict__ SE,
                            unsigned short* __restrict__ Epk2,
                            float* __restrict__ klacc) {
  int k = blockIdx.x;
  int d = threadIdx.x;
  if (k == 0 && d == 0) *klacc = 0.f;
  float v = Ew[k * DDIM + d];
  float n2 = v * v;
  #pragma unroll
  for (int o = 32; o > 0; o >>= 1) n2 += __shfl_xor(n2, o, 64);
  float m = v;
  #pragma unroll
  for (int o = 32; o > 0; o >>= 1) m = fmaxf(m, __shfl_xor(m, o, 64));
  float e = __expf(v - m);
  float Z = e;
  #pragma unroll
  for (int o = 32; o > 0; o >>= 1) Z += __shfl_xor(Z, o, 64);
  SE[k * DDIM + d] = e / Z;
  if (d == 0) enorm[k] = n2;

  unsigned int rh = bf16_rne(v);
  float hif = __uint_as_float(rh << 16);
  unsigned int rl = bf16_rne(v - hif);
  int tile = k >> 5, mm = k & 31;
  int s = d >> 4, h = (d >> 3) & 1, j = d & 7;
  int base = tile * 4096 + (h * 32 + mm) * 8 + j;
  Epk2[base + s * 512]        = (unsigned short)rh;
  Epk2[base + (4 + s) * 512]  = (unsigned short)rl;
}

// ---------------------------------------------------------------------------
// argmin FUSED (R9): counted-vmcnt double-buffered codebook pipeline.
// 512 blocks x 4 waves x 32 rows. Codebook = 16 chunks of 16 KB (2 tiles);
// per chunk: issue next chunk's 4 global_load_lds per wave -> s_waitcnt
// vmcnt(4) (current resident, next stays IN FLIGHT across the barrier) ->
// raw s_barrier -> compute 2 tiles -> raw s_barrier. Never vmcnt(0) in-loop
// (T3/T4; avoids the __syncthreads full-drain that nullified R8).
// 32 KB LDS + single 12-deep MFMA chain (R3's 108-VGPR form) -> VGPR <= ~128
// so HW can co-schedule 4 blocks/CU (launch_bounds min stays 2; no R4 clamp).
// Fused epilogue = R3-verified.
// ---------------------------------------------------------------------------
__launch_bounds__(256, 2)
__global__ void argmin_fused_kernel(const float* __restrict__ inp,
                                    const unsigned short* __restrict__ Epk2,
                                    const float* __restrict__ enorm,
                                    const float* __restrict__ SE,
                                    const float* __restrict__ Ew,
                                    int* __restrict__ idx_ws,
                                    float* __restrict__ outidx,
                                    float* __restrict__ out,
                                    float* __restrict__ klacc) {
  __shared__ unsigned short cb0[CHUNK_SHORTS];   // 16 KB
  __shared__ unsigned short cb1[CHUNK_SHORTS];   // 16 KB

  const int tid = threadIdx.x;
  const int lane = tid & 63;
  const int w = tid >> 6;
  const int half = lane >> 5;
  const int m = lane & 31;
  const int row_base = blockIdx.x * 128 + w * 32;
  const int b = row_base >> 12;
  const int l0 = row_base & 4095;
  const float* xp = inp + (size_t)b * DDIM * LDIM + l0 + m;

  // ---- issue chunk 0 (4 gloads/wave); latency overlaps the x-prologue ----
  {
    const unsigned short* s0 = Epk2 + w * 2048;
    unsigned short* d0 = cb0 + w * 2048;
    #pragma unroll
    for (int r = 0; r < 4; ++r)
      gload_lds16(s0 + r * 512 + lane * 8, d0 + r * 512);
  }

  short8 afr[8];
  float ex[4][8];          // e^x, statically indexed only (rule #20)
  float Zp = 0.f, S1p = 0.f;
  #pragma unroll
  for (int s = 0; s < 4; s++) {
    #pragma unroll
    for (int j = 0; j < 8; j++) {
      int d = 16 * s + 8 * half + j;
      float x = xp[(size_t)d * LDIM];
      float e = __expf(x);
      ex[s][j] = e;
      Zp += e;
      S1p = fmaf(e, x, S1p);
      unsigned int rh = bf16_rne(x);
      float hif = __uint_as_float(rh << 16);
      unsigned int rl = bf16_rne(x - hif);
      afr[s][j] = (short)(unsigned short)rh;
      afr[4 + s][j] = (short)(unsigned short)rl;
    }
  }

  float bsc[16];
  int bix[16];
  #pragma unroll
  for (int j = 0; j < 16; j++) { bsc[j] = 1e30f; bix[j] = 0; }

  float16v zacc = {};   // persistent zero C-in for first MFMA of each chain

  __builtin_amdgcn_sched_barrier(0);   // fence prologue VMEM from the pipeline

  #pragma unroll
  for (int c = 0; c < 16; ++c) {
    unsigned short* cur = (c & 1) ? cb1 : cb0;
    unsigned short* nxt = (c & 1) ? cb0 : cb1;
    if (c < 15) {
      const unsigned short* sn = Epk2 + (size_t)(c + 1) * CHUNK_SHORTS + w * 2048;
      unsigned short* dn = nxt + w * 2048;
      #pragma unroll
      for (int r = 0; r < 4; ++r)
        gload_lds16(sn + r * 512 + lane * 8, dn + r * 512);
      asm volatile("s_waitcnt vmcnt(4)" ::: "memory");  // cur resident; nxt in flight
    } else {
      asm volatile("s_waitcnt vmcnt(0)" ::: "memory");
    }
    __builtin_amdgcn_sched_barrier(0);
    __builtin_amdgcn_s_barrier();
    __builtin_amdgcn_sched_barrier(0);

    #pragma unroll
    for (int tt = 0; tt < 2; ++tt) {
      const int t = c * 2 + tt;
      const unsigned short* cbp = cur + tt * 4096 + lane * 8;
      short8 bA[8];
      #pragma unroll
      for (int s = 0; s < 4; s++) {
        bA[s]     = *(const short8*)(cbp + s * 512);
        bA[4 + s] = *(const short8*)(cbp + 2048 + s * 512);
      }
      float en = enorm[t * 32 + m];

      // 12-deep chained accumulation: hi*hi + hi*lo + lo*hi, all K-slices
      float16v acc = __builtin_amdgcn_mfma_f32_32x32x16_bf16(afr[0], bA[0], zacc, 0, 0, 0);
      acc = __builtin_amdgcn_mfma_f32_32x32x16_bf16(afr[0], bA[4], acc, 0, 0, 0);
      acc = __builtin_amdgcn_mfma_f32_32x32x16_bf16(afr[4], bA[0], acc, 0, 0, 0);
      #pragma unroll
      for (int s = 1; s < 4; s++) {
        acc = __builtin_amdgcn_mfma_f32_32x32x16_bf16(afr[s], bA[s], acc, 0, 0, 0);
        acc = __builtin_amdgcn_mfma_f32_32x32x16_bf16(afr[s], bA[4 + s], acc, 0, 0, 0);
        acc = __builtin_amdgcn_mfma_f32_32x32x16_bf16(afr[4 + s], bA[s], acc, 0, 0, 0);
      }
      const int ci = t * 32 + m;
      #pragma unroll
      for (int j = 0; j < 16; j++) {
        float sc = fmaf(-2.f, acc[j], en);
        if (sc < bsc[j]) { bsc[j] = sc; bix[j] = ci; }  // ascending ci: ties -> smaller
      }
    }
    __builtin_amdgcn_sched_barrier(0);
    __builtin_amdgcn_s_barrier();      // all reads of cur done before overwrite
    __builtin_amdgcn_sched_barrier(0);
  }

  // -------- per-row winner keys + fused epilogue (R3-verified) --------
  // Row m is held in key slot j_r of half h_r:
  const int jr = (m & 3) | ((m >> 3) << 2);
  const int hr = (m >> 2) & 1;
  unsigned long long mykey = 0ull;

  #pragma unroll
  for (int j = 0; j < 16; j++) {
    unsigned long long key =
        ((unsigned long long)orderf(bsc[j]) << 32) | (unsigned int)bix[j];
    #pragma unroll
    for (int mm = 1; mm < 32; mm <<= 1) {
      unsigned long long o = shfl_xor_u64(key, mm);
      if (o < key) key = o;
    }
    if (j == jr) mykey = key;   // static unroll: cndmask, no scratch
  }
  unsigned long long partner = shfl_xor_u64(mykey, 32);
  unsigned long long keyrow = (hr == half) ? mykey : partner;
  const int kr = (int)(keyrow & 0xffffffffull);

  if (half == 0) {
    idx_ws[row_base + m] = kr;
    outidx[row_base + m] = (float)kr;
  }

  // U = sum_d e^{x_d} * SE[kr][d]  (this thread's 32 d's), and out stores
  float Up = 0.f;
  const float* sebase = SE + kr * DDIM + 8 * half;
  const float* ewbase = Ew + kr * DDIM + 8 * half;
  float* obase = out + (size_t)b * DDIM * LDIM + l0 + m;
  #pragma unroll
  for (int s = 0; s < 4; s++) {
    float4 q0 = *(const float4*)(sebase + 16 * s);
    float4 q1 = *(const float4*)(sebase + 16 * s + 4);
    Up = fmaf(ex[s][0], q0.x, Up); Up = fmaf(ex[s][1], q0.y, Up);
    Up = fmaf(ex[s][2], q0.z, Up); Up = fmaf(ex[s][3], q0.w, Up);
    Up = fmaf(ex[s][4], q1.x, Up); Up = fmaf(ex[s][5], q1.y, Up);
    Up = fmaf(ex[s][6], q1.z, Up); Up = fmaf(ex[s][7], q1.w, Up);
    float4 e0 = *(const float4*)(ewbase + 16 * s);
    float4 e1 = *(const float4*)(ewbase + 16 * s + 4);
    const int d0 = 16 * s + 8 * half;
    obase[(size_t)(d0 + 0) * LDIM] = e0.x;
    obase[(size_t)(d0 + 1) * LDIM] = e0.y;
    obase[(size_t)(d0 + 2) * LDIM] = e0.z;
    obase[(size_t)(d0 + 3) * LDIM] = e0.w;
    obase[(size_t)(d0 + 4) * LDIM] = e1.x;
    obase[(size_t)(d0 + 5) * LDIM] = e1.y;
    obase[(size_t)(d0 + 6) * LDIM] = e1.z;
    obase[(size_t)(d0 + 7) * LDIM] = e1.w;
  }

  // combine half-pair (disjoint d-subsets), then per-wave KL sum
  float Z = Zp + __shfl_xor(Zp, 32, 64);
  float S1 = S1p + __shfl_xor(S1p, 32, 64);
  float U = Up + __shfl_xor(Up, 32, 64);
  float kl = (S1 - U) / Z - __logf(Z);
  kl = (half == 0) ? kl : 0.f;
  #pragma unroll
  for (int o = 1; o < 64; o <<= 1) kl += __shfl_xor(kl, o, 64);
  if (lane == 0) atomicAdd(klacc, kl);   // non-returning: no wave stall
}

// ---------------------------------------------------------------------------
// dw: dimension-sliced LDS histogram. 512 threads/block, fully-unrolled
// float4/int4 loads. (R7-verified.)
// ---------------------------------------------------------------------------
__launch_bounds__(512)
__global__ void dw_kernel(const float* __restrict__ inp,
                          const int* __restrict__ idx_ws,
                          float* __restrict__ partial,
                          float* __restrict__ pcounts) {
  __shared__ float dwp[KCODES];
  __shared__ float cnt[KCODES];
  const int tid = threadIdx.x;
  const int d = blockIdx.x & 63;
  const int slice = blockIdx.x >> 6;
  const bool do_cnt = (d == 0);

  #pragma unroll
  for (int i = 0; i < KCODES / 512; i++) {
    dwp[tid + i * 512] = 0.f;
    cnt[tid + i * 512] = 0.f;
  }
  __syncthreads();

  const int r0 = slice * SLICE_ROWS;
  #pragma unroll
  for (int j = 0; j < 4; j++) {
    const int rbase = r0 + j * 2048 + tid * 4;
    const int bb = rbase >> 12;
    const int ll = rbase & 4095;
    const float4 xv = *(const float4*)(inp + (size_t)bb * DDIM * LDIM +
                                       (size_t)d * LDIM + ll);
    const int4 kv = *(const int4*)(idx_ws + rbase);
    atomicAdd(&dwp[kv.x], xv.x);
    atomicAdd(&dwp[kv.y], xv.y);
    atomicAdd(&dwp[kv.z], xv.z);
    atomicAdd(&dwp[kv.w], xv.w);
    if (do_cnt) {
      atomicAdd(&cnt[kv.x], 1.0f);
      atomicAdd(&cnt[kv.y], 1.0f);
      atomicAdd(&cnt[kv.z], 1.0f);
      atomicAdd(&cnt[kv.w], 1.0f);
    }
  }
  __syncthreads();

  float* dst = partial + ((size_t)slice * 64 + d) * KCODES;
  #pragma unroll
  for (int i = 0; i < KCODES / 512; i++) dst[tid + i * 512] = dwp[tid + i * 512];
  if (do_cnt) {
    float* cd = pcounts + (size_t)slice * KCODES;
    #pragma unroll
    for (int i = 0; i < KCODES / 512; i++) cd[tid + i * 512] = cnt[tid + i * 512];
  }
}

// ---------------------------------------------------------------------------
// finalize: COALESCED mapping (R7-verified). Block b -> d = b>>2,
// k = (b&3)*256+tid; partial/pcounts/emacs reads contiguous along k.
// ---------------------------------------------------------------------------
__launch_bounds__(256)
__global__ void finalize_kernel(const float* __restrict__ partial,
                                const float* __restrict__ pcounts,
                                const float* __restrict__ emaw,
                                const float* __restrict__ emacs,
                                const float* __restrict__ klacc,
                                float* __restrict__ emb_out,
                                float* __restrict__ loss_out,
                                float* __restrict__ perp_out) {
  __shared__ float red[4], red2[4];
  const int tid = threadIdx.x;
  const int d = blockIdx.x >> 2;
  const int k = ((blockIdx.x & 3) << 8) + tid;

  float se = 0.f;
  #pragma unroll
  for (int t = 0; t < 4; t++) se += emacs[tid * 4 + t];
  #pragma unroll
  for (int o = 32; o > 0; o >>= 1) se += __shfl_xor(se, o, 64);
  if ((tid & 63) == 0) red[tid >> 6] = se;
  __syncthreads();
  const float S = red[0] + red[1] + red[2] + red[3];
  const float N = 0.9f * S + 0.1f * (float)NROWS;

  float c = 0.f;
  #pragma unroll
  for (int sl = 0; sl < NSLICE; sl++) c += pcounts[sl * KCODES + k];
  float cs = fmaf(0.1f, c, emacs[k] * 0.9f);
  float csp = (cs + 1e-5f) / (N + (float)KCODES * 1e-5f) * N;

  float s = 0.f;
  #pragma unroll
  for (int sl = 0; sl < NSLICE; sl++)
    s += partial[((size_t)sl * 64 + d) * KCODES + k];
  emb_out[k * DDIM + d] = fmaf(0.1f, s, emaw[k * DDIM + d] * 0.9f) / csp;

  if (blockIdx.x == 0) {
    float es = 0.f;
    #pragma unroll
    for (int t = 0; t < 4; t++) {
      int kk = tid * 4 + t;
      float cc = 0.f;
      #pragma unroll
      for (int sl = 0; sl < NSLICE; sl++) cc += pcounts[sl * KCODES + kk];
      float a = cc * (1.0f / (float)NROWS);
      es += a * logf(a + 1e-10f);
    }
    #pragma unroll
    for (int o = 32; o > 0; o >>= 1) es += __shfl_xor(es, o, 64);
    if ((tid & 63) == 0) red2[tid >> 6] = es;
    __syncthreads();
    if (tid == 0) {
      *perp_out = expf(-(red2[0] + red2[1] + red2[2] + red2[3]));
      *loss_out = 0.1f * (*klacc) * (1.0f / 16.0f);
    }
  }
}

extern "C" void kernel_launch(void* const* d_in, const int* in_sizes, int n_in,
                              void* d_out, int out_size, void* d_ws, size_t ws_size,
                              hipStream_t stream) {
  const float* inp   = (const float*)d_in[0];   // (16,64,4096)
  const float* Ew    = (const float*)d_in[1];   // (1024,64)
  const float* emacs = (const float*)d_in[2];   // (1024,)
  const float* emaw  = (const float*)d_in[3];   // (1024,64)

  float* out      = (float*)d_out;              // (16,64,4096) = 4194304
  float* loss_out = out + 4194304;
  float* perp_out = out + 4194305;
  float* emb_out  = out + 4194306;              // 65536
  float* idxf_out = out + 4194306 + 65536;      // 65536 (indices as float)

  char* ws = (char*)d_ws;
  int*   idx_ws  = (int*)(ws);                  // 262144 B
  float* klacc   = (float*)(ws + 262144);       // 256 B (zeroed by prep)
  float* enorm   = (float*)(ws + 266496);       // 4096 B
  float* SE      = (float*)(ws + 274688);       // 262144 B -> ends 536832
  unsigned short* Epk2 = (unsigned short*)(ws + 536832);  // 262144 B
  // dw partials alias Epk2 (dead after argmin)
  float* partial = (float*)(ws + 536832);       // 2097152 B -> ends 2633984
  float* pcounts = (float*)(ws + 2633984);      // 32768 B  -> ends 2666752

  prep_kernel<<<KCODES, 64, 0, stream>>>(Ew, enorm, SE, Epk2, klacc);
  argmin_fused_kernel<<<512, 256, 0, stream>>>(inp, Epk2, enorm, SE, Ew,
                                               idx_ws, idxf_out, out, klacc);
  dw_kernel<<<512, 512, 0, stream>>>(inp, idx_ws, partial, pcounts);
  finalize_kernel<<<NROWS / 256, 256, 0, stream>>>(partial, pcounts, emaw, emacs,
                                                   klacc, emb_out, loss_out,
                                                   perp_out);
}